// Round 2
// baseline (47546.466 us; speedup 1.0000x reference)
//
#include <hip/hip_runtime.h>
#include <stdint.h>

// LSTM persistent kernel, round 2. 256 WGs x 512 thr, 1 WG/CU pinned.
// WG(p,q): batch pair p (rows 2p,2p+1) x hidden quarter q (units q*64..+64).
// Weights: 256 rows x 384 K fp16 = 96 dwords/thread held in 24 NAMED uint4
// vars (macro-scalarized -> guaranteed VGPRs; round-1 array went to scratch
// and made the kernel L3-BW-bound at 26.9 ms).
// Per step: 192 dot2/thread from LDS hx=[x_t|h], shfl_xor butterfly over the
// 8 K-slice lanes (no LDS partials), cell update + c in registers of the
// (jj,row) lanes, quartet h-exchange via agent-scope flags in d_ws.

#define T_SEQ 2048
#define BATCH 128
#define IN_D  128
#define HID   256
#define OUTD  64

typedef _Float16 half2_t __attribute__((ext_vector_type(2)));

__device__ __forceinline__ float dot2f(uint32_t w, uint32_t h, float acc) {
#if __has_builtin(__builtin_amdgcn_fdot2)
  return __builtin_amdgcn_fdot2(__builtin_bit_cast(half2_t, w),
                                __builtin_bit_cast(half2_t, h), acc, false);
#else
  half2_t a = __builtin_bit_cast(half2_t, w);
  half2_t b = __builtin_bit_cast(half2_t, h);
  return acc + (float)a[0] * (float)b[0] + (float)a[1] * (float)b[1];
#endif
}

__device__ __forceinline__ uint32_t pack2(float a, float b) {
  union { _Float16 h[2]; uint32_t u; } u_;
  u_.h[0] = (_Float16)a; u_.h[1] = (_Float16)b;
  return u_.u;
}

// load 8 fused-K fp16 weights (cols k..k+7) for row `row` of [W_ih|W_hh]
__device__ __forceinline__ uint4 load8(const float* __restrict__ Wih,
                                       const float* __restrict__ Whh,
                                       int row, int k) {
  const float* p0 = (k     < IN_D) ? (Wih + (size_t)row * IN_D + k)
                                   : (Whh + (size_t)row * HID + (k - IN_D));
  const float* p1 = (k + 4 < IN_D) ? (Wih + (size_t)row * IN_D + k + 4)
                                   : (Whh + (size_t)row * HID + (k + 4 - IN_D));
  const float4 a = *(const float4*)p0;
  const float4 b = *(const float4*)p1;
  uint4 r;
  r.x = pack2(a.x, a.y); r.y = pack2(a.z, a.w);
  r.z = pack2(b.x, b.y); r.w = pack2(b.z, b.w);
  return r;
}

__device__ __forceinline__ float sigm(float v) { return 1.f / (1.f + __expf(-v)); }
__device__ __forceinline__ float tanhx(float v) {
  float a = fabsf(v);
  float e = __expf(2.f * a);
  float r = 1.f - 2.f / (e + 1.f);
  return v < 0.f ? -r : r;
}

#define DOT_U(g, u, A)                      \
  A = dot2f(W##g##_##u.x, hv0_.x, A);       \
  A = dot2f(W##g##_##u.y, hv0_.y, A);       \
  A = dot2f(W##g##_##u.z, hv0_.z, A);       \
  A = dot2f(W##g##_##u.w, hv0_.w, A);

#define DOT_G(g, A)                                            \
  { const uint4 hv0_ = hp[0]; DOT_U(g, 0, A) }                 \
  { const uint4 hv0_ = hp[1]; DOT_U(g, 1, A) }                 \
  { const uint4 hv0_ = hp[2]; DOT_U(g, 2, A) }                 \
  { const uint4 hv0_ = hp[3]; DOT_U(g, 3, A) }                 \
  { const uint4 hv0_ = hp[4]; DOT_U(g, 4, A) }                 \
  { const uint4 hv0_ = hp[5]; DOT_U(g, 5, A) }

#define BFLY3(v)                 \
  v += __shfl_xor(v, 1, 64);     \
  v += __shfl_xor(v, 2, 64);     \
  v += __shfl_xor(v, 4, 64);

__global__ __launch_bounds__(512)
__attribute__((amdgpu_waves_per_eu(2, 2)))
void lstm_persist(const float* __restrict__ x,   const float* __restrict__ Wih,
                  const float* __restrict__ Whh, const float* __restrict__ bih,
                  const float* __restrict__ bhh, const float* __restrict__ Wout,
                  const float* __restrict__ bout_g, float* __restrict__ out,
                  uint32_t* flags, uint32_t* exch)
{
  // hx: 2 rows x 192 dwords of fp16 pairs; row = [x_t(128 fp16) | h(256 fp16)]
  __shared__ alignas(16) uint32_t hx[2 * 192];

  const int tid = threadIdx.x;
  const int w   = blockIdx.x;
  const int p   = w >> 2;                 // batch pair -> rows 2p, 2p+1
  const int q   = w & 3;                  // hidden quarter
  const int jj  = tid >> 3;               // 0..63 hidden unit within quarter
  const int ks  = tid & 7;                // 0..7 K-slice (48 fused K each)
  const int rbase = (q << 6) + jj;        // gate-row base within a gate block
  const int kb    = ks * 48;

  // ---- weights: 24 named uint4 (96 dwords) — MUST be VGPRs
  uint4 W0_0, W0_1, W0_2, W0_3, W0_4, W0_5;
  uint4 W1_0, W1_1, W1_2, W1_3, W1_4, W1_5;
  uint4 W2_0, W2_1, W2_2, W2_3, W2_4, W2_5;
  uint4 W3_0, W3_1, W3_2, W3_3, W3_4, W3_5;
#define LOADG(g)                                             \
  { const int row = (g) * HID + rbase;                       \
    W##g##_0 = load8(Wih, Whh, row, kb +  0);                \
    W##g##_1 = load8(Wih, Whh, row, kb +  8);                \
    W##g##_2 = load8(Wih, Whh, row, kb + 16);                \
    W##g##_3 = load8(Wih, Whh, row, kb + 24);                \
    W##g##_4 = load8(Wih, Whh, row, kb + 32);                \
    W##g##_5 = load8(Wih, Whh, row, kb + 40); }
  LOADG(0) LOADG(1) LOADG(2) LOADG(3)
#undef LOADG

  // ---- gate biases (used by ks<2 lanes)
  float b0 = bih[0 * HID + rbase] + bhh[0 * HID + rbase];
  float b1 = bih[1 * HID + rbase] + bhh[1 * HID + rbase];
  float b2 = bih[2 * HID + rbase] + bhh[2 * HID + rbase];
  float b3 = bih[3 * HID + rbase] + bhh[3 * HID + rbase];

  // ---- out-projection: thread (oo,r,os): o = q*16+oo, K-slice os*16..+16
  const int oo = tid >> 5, orow = (tid >> 4) & 1, os = tid & 15;
  uint4 woA, woB;
  {
    const float* wo = Wout + (size_t)((q << 4) + oo) * HID + (os << 4);
    const float4 v0 = *(const float4*)(wo + 0), v1 = *(const float4*)(wo + 4);
    const float4 v2 = *(const float4*)(wo + 8), v3 = *(const float4*)(wo + 12);
    woA.x = pack2(v0.x, v0.y); woA.y = pack2(v0.z, v0.w);
    woA.z = pack2(v1.x, v1.y); woA.w = pack2(v1.z, v1.w);
    woB.x = pack2(v2.x, v2.y); woB.y = pack2(v2.z, v2.w);
    woB.z = pack2(v3.x, v3.y); woB.w = pack2(v3.z, v3.w);
  }
  const float bo = bout_g[(q << 4) + oo];

  // ---- init hx: h=0, x-part = x[0]
  if (tid < 256) hx[(tid >> 7) * 192 + 64 + (tid & 127)] = 0u;
  if (tid < 128) {
    const int row = tid >> 6, cc = tid & 63;
    const float2 xv = *(const float2*)(x + ((size_t)(2 * p + row)) * IN_D + 2 * cc);
    hx[row * 192 + cc] = pack2(xv.x, xv.y);
  }
  float c = 0.f;
  __syncthreads();

  for (int t = 0; t <= T_SEQ; ++t) {
    uint32_t xn = 0;
    unsigned short hu = 0;
    // ---------------- phase 1 ----------------
    if (t < T_SEQ) {
      if (tid >= 256 && tid < 384 && (t + 1) < T_SEQ) {
        const int row = (tid - 256) >> 6, cc = (tid - 256) & 63;
        const float2 xv = *(const float2*)(x + (size_t)(t + 1) * BATCH * IN_D +
                                           (size_t)(2 * p + row) * IN_D + 2 * cc);
        xn = pack2(xv.x, xv.y);
      }
      float a00 = 0.f, a10 = 0.f, a20 = 0.f, a30 = 0.f;
      float a01 = 0.f, a11 = 0.f, a21 = 0.f, a31 = 0.f;
      {
        const uint4* hp = (const uint4*)hx + ks * 6;           // row 0
        DOT_G(0, a00) DOT_G(1, a10) DOT_G(2, a20) DOT_G(3, a30)
      }
      {
        const uint4* hp = (const uint4*)hx + 48 + ks * 6;      // row 1
        DOT_G(0, a01) DOT_G(1, a11) DOT_G(2, a21) DOT_G(3, a31)
      }
      BFLY3(a00) BFLY3(a10) BFLY3(a20) BFLY3(a30)
      BFLY3(a01) BFLY3(a11) BFLY3(a21) BFLY3(a31)
      if (ks < 2) {
        const int r = ks;
        const float gi = b0 + (r ? a01 : a00);
        const float gf = b1 + (r ? a11 : a10);
        const float gg = b2 + (r ? a21 : a20);
        const float go = b3 + (r ? a31 : a30);
        const float iv = sigm(gi), fv = sigm(gf), gv = tanhx(gg), ov = sigm(go);
        c = fv * c + iv * gv;
        const float hn = ov * tanhx(c);
        union { _Float16 h; unsigned short u; } cv; cv.h = (_Float16)hn;
        hu = cv.u;
        // publish own h to global exch (ring slot), pre-barrier
        ((volatile unsigned short*)exch)[((w * 2 + (t & 1)) << 7) + (r << 6) + jj] = hu;
      }
    }
    if (t >= 1) {  // out-projection for step t-1 from h(t-1) still in hx
      const uint4* hq = (const uint4*)hx + orow * 48 + 16 + os * 2;
      const uint4 h0 = hq[0], h1 = hq[1];
      float oa = 0.f;
      oa = dot2f(woA.x, h0.x, oa); oa = dot2f(woA.y, h0.y, oa);
      oa = dot2f(woA.z, h0.z, oa); oa = dot2f(woA.w, h0.w, oa);
      oa = dot2f(woB.x, h1.x, oa); oa = dot2f(woB.y, h1.y, oa);
      oa = dot2f(woB.z, h1.z, oa); oa = dot2f(woB.w, h1.w, oa);
      oa += __shfl_xor(oa, 1, 64); oa += __shfl_xor(oa, 2, 64);
      oa += __shfl_xor(oa, 4, 64); oa += __shfl_xor(oa, 8, 64);
      if (os == 0)
        out[((size_t)(t - 1) * BATCH + 2 * p + orow) * OUTD + (q << 4) + oo] = oa + bo;
    }
    __syncthreads();  // B1: all hx reads done; exch stores drained (vmcnt 0)
    // ---------------- phase 2 ----------------
    if (t < T_SEQ) {
      if (ks < 2)  // write own h into hx
        ((unsigned short*)hx)[ks * 384 + 128 + (q << 6) + jj] = hu;
      if (tid == 0) {
        __threadfence();
        __hip_atomic_store(flags + w, (uint32_t)(t + 1),
                           __ATOMIC_RELEASE, __HIP_MEMORY_SCOPE_AGENT);
      }
      if (tid >= 256 && tid < 384 && (t + 1) < T_SEQ)
        hx[((tid - 256) >> 6) * 192 + ((tid - 256) & 63)] = xn;
      if (tid >= 64 && tid < 256) {  // consume 3 partner quarters
        const int i = tid - 64, qq = i >> 6, l = i & 63;
        const int qp = qq + (qq >= q);           // partner quarter != q
        const int ws = (w & ~3) | qp;
        const uint32_t want = (uint32_t)(t + 1);
        while (__hip_atomic_load(flags + ws, __ATOMIC_RELAXED,
                                 __HIP_MEMORY_SCOPE_AGENT) < want) {}
        __threadfence();
        const uint32_t v = __hip_atomic_load(
            exch + (((size_t)ws * 2 + (t & 1)) << 6) + l,
            __ATOMIC_RELAXED, __HIP_MEMORY_SCOPE_AGENT);
        hx[(l >> 5) * 192 + 64 + (qp << 5) + (l & 31)] = v;
      }
    }
    __syncthreads();  // B2: hx fully assembled for step t+1
  }
}

extern "C" void kernel_launch(void* const* d_in, const int* in_sizes, int n_in,
                              void* d_out, int out_size, void* d_ws, size_t ws_size,
                              hipStream_t stream) {
  (void)in_sizes; (void)n_in; (void)out_size; (void)ws_size;
  const float* x    = (const float*)d_in[0];
  const float* Wih  = (const float*)d_in[1];
  const float* Whh  = (const float*)d_in[2];
  const float* bih  = (const float*)d_in[3];
  const float* bhh  = (const float*)d_in[4];
  const float* Wout = (const float*)d_in[5];
  const float* bout = (const float*)d_in[6];
  float* out = (float*)d_out;

  uint32_t* flags = (uint32_t*)d_ws;                   // 256 dwords
  uint32_t* exch  = (uint32_t*)((char*)d_ws + 1024);   // 256 WG x 2 ring x 64 dwords

  hipMemsetAsync(d_ws, 0, 1024, stream);               // flags must start at 0
  hipLaunchKernelGGL(lstm_persist, dim3(256), dim3(512), 0, stream,
                     x, Wih, Whh, bih, bhh, Wout, bout, out, flags, exch);
}

// Round 3
// 45897.406 us; speedup vs baseline: 1.0359x; 1.0359x over previous
//
#include <hip/hip_runtime.h>
#include <stdint.h>

// LSTM persistent kernel, round 3. 256 WGs x 512 thr, 1 WG/CU.
// WG(p,q): batch pair p (rows 2p,2p+1) x hidden quarter q (units q*64..+64).
// Weights: 96 dwords/thread (fp16 pairs) in 24 named uint4, PINNED into VGPRs
// via asm volatile (round 2: allocator targeted 128 VGPRs and rematerialized
// the weight loads inside the loop -> 44.5 ms). __launch_bounds__(512,2)
// gives the 256-VGPR budget (2 waves/EU min).
// Per step: 192 dot2/thread from LDS hx=[x_t|h], select-tree shuffle
// reduction (16 shuffles), cell update in lanes ks<2, quartet h-exchange
// via agent-scope flags in d_ws, fused out-projection.

#define T_SEQ 2048
#define BATCH 128
#define IN_D  128
#define HID   256
#define OUTD  64

typedef _Float16 half2_t __attribute__((ext_vector_type(2)));

__device__ __forceinline__ float dot2f(uint32_t w, uint32_t h, float acc) {
#if __has_builtin(__builtin_amdgcn_fdot2)
  return __builtin_amdgcn_fdot2(__builtin_bit_cast(half2_t, w),
                                __builtin_bit_cast(half2_t, h), acc, false);
#else
  half2_t a = __builtin_bit_cast(half2_t, w);
  half2_t b = __builtin_bit_cast(half2_t, h);
  return acc + (float)a[0] * (float)b[0] + (float)a[1] * (float)b[1];
#endif
}

__device__ __forceinline__ uint32_t pack2(float a, float b) {
  union { _Float16 h[2]; uint32_t u; } u_;
  u_.h[0] = (_Float16)a; u_.h[1] = (_Float16)b;
  return u_.u;
}

// load 8 fused-K fp16 weights (cols k..k+7) for row `row` of [W_ih|W_hh]
__device__ __forceinline__ uint4 load8(const float* __restrict__ Wih,
                                       const float* __restrict__ Whh,
                                       int row, int k) {
  const float* p0 = (k     < IN_D) ? (Wih + (size_t)row * IN_D + k)
                                   : (Whh + (size_t)row * HID + (k - IN_D));
  const float* p1 = (k + 4 < IN_D) ? (Wih + (size_t)row * IN_D + k + 4)
                                   : (Whh + (size_t)row * HID + (k + 4 - IN_D));
  const float4 a = *(const float4*)p0;
  const float4 b = *(const float4*)p1;
  uint4 r;
  r.x = pack2(a.x, a.y); r.y = pack2(a.z, a.w);
  r.z = pack2(b.x, b.y); r.w = pack2(b.z, b.w);
  return r;
}

__device__ __forceinline__ float sigm(float v) { return 1.f / (1.f + __expf(-v)); }
__device__ __forceinline__ float tanhx(float v) {
  float a = fabsf(v);
  float e = __expf(2.f * a);
  float r = 1.f - 2.f / (e + 1.f);
  return v < 0.f ? -r : r;
}

#define DOT_U(g, u, A)                      \
  A = dot2f(W##g##_##u.x, hv0_.x, A);       \
  A = dot2f(W##g##_##u.y, hv0_.y, A);       \
  A = dot2f(W##g##_##u.z, hv0_.z, A);       \
  A = dot2f(W##g##_##u.w, hv0_.w, A);

#define DOT_G(g, A)                                            \
  { const uint4 hv0_ = hp[0]; DOT_U(g, 0, A) }                 \
  { const uint4 hv0_ = hp[1]; DOT_U(g, 1, A) }                 \
  { const uint4 hv0_ = hp[2]; DOT_U(g, 2, A) }                 \
  { const uint4 hv0_ = hp[3]; DOT_U(g, 3, A) }                 \
  { const uint4 hv0_ = hp[4]; DOT_U(g, 4, A) }                 \
  { const uint4 hv0_ = hp[5]; DOT_U(g, 5, A) }

// pin a uint4 into VGPRs: volatile asm cannot be remat'd/sunk/deleted
#define PIN4(v) asm volatile("" : "+v"(v.x), "+v"(v.y), "+v"(v.z), "+v"(v.w));

__global__ __launch_bounds__(512, 2)
void lstm_persist(const float* __restrict__ x,   const float* __restrict__ Wih,
                  const float* __restrict__ Whh, const float* __restrict__ bih,
                  const float* __restrict__ bhh, const float* __restrict__ Wout,
                  const float* __restrict__ bout_g, float* __restrict__ out,
                  uint32_t* flags, uint32_t* exch)
{
  // hx: 2 rows x 192 dwords of fp16 pairs; row = [x_t(128 fp16) | h(256 fp16)]
  __shared__ alignas(16) uint32_t hx[2 * 192];

  const int tid = threadIdx.x;
  const int w   = blockIdx.x;
  const int p   = w >> 2;                 // batch pair -> rows 2p, 2p+1
  const int q   = w & 3;                  // hidden quarter
  const int jj  = tid >> 3;               // 0..63 hidden unit within quarter
  const int ks  = tid & 7;                // 0..7 K-slice (48 fused K each)
  const int rbase = (q << 6) + jj;        // gate-row base within a gate block
  const int kb    = ks * 48;

  // ---- weights: 24 named uint4 (96 dwords), pinned to VGPRs
  uint4 W0_0, W0_1, W0_2, W0_3, W0_4, W0_5;
  uint4 W1_0, W1_1, W1_2, W1_3, W1_4, W1_5;
  uint4 W2_0, W2_1, W2_2, W2_3, W2_4, W2_5;
  uint4 W3_0, W3_1, W3_2, W3_3, W3_4, W3_5;
#define LOADG(g)                                             \
  { const int row = (g) * HID + rbase;                       \
    W##g##_0 = load8(Wih, Whh, row, kb +  0);                \
    W##g##_1 = load8(Wih, Whh, row, kb +  8);                \
    W##g##_2 = load8(Wih, Whh, row, kb + 16);                \
    W##g##_3 = load8(Wih, Whh, row, kb + 24);                \
    W##g##_4 = load8(Wih, Whh, row, kb + 32);                \
    W##g##_5 = load8(Wih, Whh, row, kb + 40); }
  LOADG(0) LOADG(1) LOADG(2) LOADG(3)
#undef LOADG
  PIN4(W0_0) PIN4(W0_1) PIN4(W0_2) PIN4(W0_3) PIN4(W0_4) PIN4(W0_5)
  PIN4(W1_0) PIN4(W1_1) PIN4(W1_2) PIN4(W1_3) PIN4(W1_4) PIN4(W1_5)
  PIN4(W2_0) PIN4(W2_1) PIN4(W2_2) PIN4(W2_3) PIN4(W2_4) PIN4(W2_5)
  PIN4(W3_0) PIN4(W3_1) PIN4(W3_2) PIN4(W3_3) PIN4(W3_4) PIN4(W3_5)

  // ---- gate biases (used by ks<2 lanes)
  float b0 = bih[0 * HID + rbase] + bhh[0 * HID + rbase];
  float b1 = bih[1 * HID + rbase] + bhh[1 * HID + rbase];
  float b2 = bih[2 * HID + rbase] + bhh[2 * HID + rbase];
  float b3 = bih[3 * HID + rbase] + bhh[3 * HID + rbase];

  // ---- out-projection: thread (oo,r,os): o = q*16+oo, K-slice os*16..+16
  const int oo = tid >> 5, orow = (tid >> 4) & 1, os = tid & 15;
  uint4 woA, woB;
  {
    const float* wo = Wout + (size_t)((q << 4) + oo) * HID + (os << 4);
    const float4 v0 = *(const float4*)(wo + 0), v1 = *(const float4*)(wo + 4);
    const float4 v2 = *(const float4*)(wo + 8), v3 = *(const float4*)(wo + 12);
    woA.x = pack2(v0.x, v0.y); woA.y = pack2(v0.z, v0.w);
    woA.z = pack2(v1.x, v1.y); woA.w = pack2(v1.z, v1.w);
    woB.x = pack2(v2.x, v2.y); woB.y = pack2(v2.z, v2.w);
    woB.z = pack2(v3.x, v3.y); woB.w = pack2(v3.z, v3.w);
  }
  PIN4(woA) PIN4(woB)
  const float bo = bout_g[(q << 4) + oo];

  // ---- init hx: h=0, x-part = x[0]
  if (tid < 256) hx[(tid >> 7) * 192 + 64 + (tid & 127)] = 0u;
  if (tid < 128) {
    const int row = tid >> 6, cc = tid & 63;
    const float2 xv = *(const float2*)(x + ((size_t)(2 * p + row)) * IN_D + 2 * cc);
    hx[row * 192 + cc] = pack2(xv.x, xv.y);
  }
  float c = 0.f;
  __syncthreads();

  for (int t = 0; t <= T_SEQ; ++t) {
    uint32_t xn = 0;
    unsigned short hu = 0;
    // ---------------- phase 1 ----------------
    if (t < T_SEQ) {
      if (tid >= 256 && tid < 384 && (t + 1) < T_SEQ) {
        const int row = (tid - 256) >> 6, cc = (tid - 256) & 63;
        const float2 xv = *(const float2*)(x + (size_t)(t + 1) * BATCH * IN_D +
                                           (size_t)(2 * p + row) * IN_D + 2 * cc);
        xn = pack2(xv.x, xv.y);
      }
      float a00 = 0.f, a10 = 0.f, a20 = 0.f, a30 = 0.f;
      float a01 = 0.f, a11 = 0.f, a21 = 0.f, a31 = 0.f;
      {
        const uint4* hp = (const uint4*)hx + ks * 6;           // row 0
        DOT_G(0, a00) DOT_G(1, a10) DOT_G(2, a20) DOT_G(3, a30)
      }
      {
        const uint4* hp = (const uint4*)hx + 48 + ks * 6;      // row 1
        DOT_G(0, a01) DOT_G(1, a11) DOT_G(2, a21) DOT_G(3, a31)
      }
      // select-tree reduction over the 8 ks lanes (16 shuffles):
      // stage 1: pair-sum over bit0, then pick row by bit0
      float u0, u1, u2, u3;
      {
        const int r = ks & 1;
        float t0, t1;
        t0 = a00 + __shfl_xor(a00, 1, 64); t1 = a01 + __shfl_xor(a01, 1, 64);
        u0 = r ? t1 : t0;
        t0 = a10 + __shfl_xor(a10, 1, 64); t1 = a11 + __shfl_xor(a11, 1, 64);
        u1 = r ? t1 : t0;
        t0 = a20 + __shfl_xor(a20, 1, 64); t1 = a21 + __shfl_xor(a21, 1, 64);
        u2 = r ? t1 : t0;
        t0 = a30 + __shfl_xor(a30, 1, 64); t1 = a31 + __shfl_xor(a31, 1, 64);
        u3 = r ? t1 : t0;
      }
      u0 += __shfl_xor(u0, 2, 64); u0 += __shfl_xor(u0, 4, 64);
      u1 += __shfl_xor(u1, 2, 64); u1 += __shfl_xor(u1, 4, 64);
      u2 += __shfl_xor(u2, 2, 64); u2 += __shfl_xor(u2, 4, 64);
      u3 += __shfl_xor(u3, 2, 64); u3 += __shfl_xor(u3, 4, 64);
      if (ks < 2) {   // lane ks holds all 4 gates for row r=ks
        const int r = ks;
        const float iv = sigm(b0 + u0), fv = sigm(b1 + u1);
        const float gv = tanhx(b2 + u2), ov = sigm(b3 + u3);
        c = fv * c + iv * gv;
        const float hn = ov * tanhx(c);
        union { _Float16 h; unsigned short u; } cv; cv.h = (_Float16)hn;
        hu = cv.u;
        // publish own h to global exch (ring slot), pre-barrier
        ((volatile unsigned short*)exch)[((w * 2 + (t & 1)) << 7) + (r << 6) + jj] = hu;
      }
    }
    if (t >= 1) {  // out-projection for step t-1 from h(t-1) still in hx
      const uint4* hq = (const uint4*)hx + orow * 48 + 16 + os * 2;
      const uint4 h0 = hq[0], h1 = hq[1];
      float oa = 0.f;
      oa = dot2f(woA.x, h0.x, oa); oa = dot2f(woA.y, h0.y, oa);
      oa = dot2f(woA.z, h0.z, oa); oa = dot2f(woA.w, h0.w, oa);
      oa = dot2f(woB.x, h1.x, oa); oa = dot2f(woB.y, h1.y, oa);
      oa = dot2f(woB.z, h1.z, oa); oa = dot2f(woB.w, h1.w, oa);
      oa += __shfl_xor(oa, 1, 64); oa += __shfl_xor(oa, 2, 64);
      oa += __shfl_xor(oa, 4, 64); oa += __shfl_xor(oa, 8, 64);
      if (os == 0)
        out[((size_t)(t - 1) * BATCH + 2 * p + orow) * OUTD + (q << 4) + oo] = oa + bo;
    }
    __syncthreads();  // B1: all hx reads done; exch stores drained (vmcnt 0)
    // ---------------- phase 2 ----------------
    if (t < T_SEQ) {
      if (ks < 2)  // write own h into hx
        ((unsigned short*)hx)[ks * 384 + 128 + (q << 6) + jj] = hu;
      if (tid == 0) {
        __threadfence();
        __hip_atomic_store(flags + w, (uint32_t)(t + 1),
                           __ATOMIC_RELEASE, __HIP_MEMORY_SCOPE_AGENT);
      }
      if (tid >= 256 && tid < 384 && (t + 1) < T_SEQ)
        hx[((tid - 256) >> 6) * 192 + ((tid - 256) & 63)] = xn;
      if (tid >= 64 && tid < 256) {  // consume 3 partner quarters
        const int i = tid - 64, qq = i >> 6, l = i & 63;
        const int qp = qq + (qq >= q);           // partner quarter != q
        const int ws = (w & ~3) | qp;
        const uint32_t want = (uint32_t)(t + 1);
        while (__hip_atomic_load(flags + ws, __ATOMIC_RELAXED,
                                 __HIP_MEMORY_SCOPE_AGENT) < want) {}
        __threadfence();
        const uint32_t v = __hip_atomic_load(
            exch + (((size_t)ws * 2 + (t & 1)) << 6) + l,
            __ATOMIC_RELAXED, __HIP_MEMORY_SCOPE_AGENT);
        hx[(l >> 5) * 192 + 64 + (qp << 5) + (l & 31)] = v;
      }
    }
    __syncthreads();  // B2: hx fully assembled for step t+1
  }
}

extern "C" void kernel_launch(void* const* d_in, const int* in_sizes, int n_in,
                              void* d_out, int out_size, void* d_ws, size_t ws_size,
                              hipStream_t stream) {
  (void)in_sizes; (void)n_in; (void)out_size; (void)ws_size;
  const float* x    = (const float*)d_in[0];
  const float* Wih  = (const float*)d_in[1];
  const float* Whh  = (const float*)d_in[2];
  const float* bih  = (const float*)d_in[3];
  const float* bhh  = (const float*)d_in[4];
  const float* Wout = (const float*)d_in[5];
  const float* bout = (const float*)d_in[6];
  float* out = (float*)d_out;

  uint32_t* flags = (uint32_t*)d_ws;                   // 256 dwords
  uint32_t* exch  = (uint32_t*)((char*)d_ws + 1024);   // 256 WG x 2 ring x 64 dwords

  hipMemsetAsync(d_ws, 0, 1024, stream);               // flags must start at 0
  hipLaunchKernelGGL(lstm_persist, dim3(256), dim3(512), 0, stream,
                     x, Wih, Whh, bih, bhh, Wout, bout, out, flags, exch);
}

// Round 5
// 4881.322 us; speedup vs baseline: 9.7405x; 9.4027x over previous
//
#include <hip/hip_runtime.h>
#include <stdint.h>

// LSTM persistent kernel, round 5. 256 WGs x 512 thr, 1 WG/CU.
// WG(p,q): p = w&63 batch pair (rows 2p,2p+1), q = w>>6 hidden quarter.
// Quartet {p, p+64, p+128, p+192} -> same XCD under round-robin %8 dispatch.
//
// Exchange protocol (round-5): SELF-VALIDATING 8B entries. Each h-pair is
// published as one aligned uint64 {hi: tag = t+1, lo: 2 x fp16} via relaxed
// agent-scope atomic store; consumers poll the SAME 8B word until tag==t+1
// and take the data from that load. No flags, no fences, no multi-address
// ordering (round 4's flag raced ahead of its data; round 3's threadfence
// fixed that by buffer_wbl2/inv at ~20us/step of L2 destruction).
// Ring-2 slots + exact tags: overwrite-safe (producer reuses a slot at t+2
// only after observing partners' t+2 publishes, which post-date their reads
// of its t entries). Poison tag 0xAAAAAAAA never matches tags 1..2048.
//
// Weights: 96 dwords/thread fp16 pairs in 24 named uint4, asm-pinned to
// VGPRs; dot2 GEMV from LDS hx=[x_t|h]; select-tree shuffle reduction;
// fused out-projection.

#define T_SEQ 2048
#define BATCH 128
#define IN_D  128
#define HID   256
#define OUTD  64

typedef _Float16 half2_t __attribute__((ext_vector_type(2)));

__device__ __forceinline__ float dot2f(uint32_t w, uint32_t h, float acc) {
#if __has_builtin(__builtin_amdgcn_fdot2)
  return __builtin_amdgcn_fdot2(__builtin_bit_cast(half2_t, w),
                                __builtin_bit_cast(half2_t, h), acc, false);
#else
  half2_t a = __builtin_bit_cast(half2_t, w);
  half2_t b = __builtin_bit_cast(half2_t, h);
  return acc + (float)a[0] * (float)b[0] + (float)a[1] * (float)b[1];
#endif
}

__device__ __forceinline__ uint32_t pack2(float a, float b) {
  union { _Float16 h[2]; uint32_t u; } u_;
  u_.h[0] = (_Float16)a; u_.h[1] = (_Float16)b;
  return u_.u;
}

// load 8 fused-K fp16 weights (cols k..k+7) for row `row` of [W_ih|W_hh]
__device__ __forceinline__ uint4 load8(const float* __restrict__ Wih,
                                       const float* __restrict__ Whh,
                                       int row, int k) {
  const float* p0 = (k     < IN_D) ? (Wih + (size_t)row * IN_D + k)
                                   : (Whh + (size_t)row * HID + (k - IN_D));
  const float* p1 = (k + 4 < IN_D) ? (Wih + (size_t)row * IN_D + k + 4)
                                   : (Whh + (size_t)row * HID + (k + 4 - IN_D));
  const float4 a = *(const float4*)p0;
  const float4 b = *(const float4*)p1;
  uint4 r;
  r.x = pack2(a.x, a.y); r.y = pack2(a.z, a.w);
  r.z = pack2(b.x, b.y); r.w = pack2(b.z, b.w);
  return r;
}

__device__ __forceinline__ float sigm(float v) { return 1.f / (1.f + __expf(-v)); }
__device__ __forceinline__ float tanhx(float v) {
  float a = fabsf(v);
  float e = __expf(2.f * a);
  float r = 1.f - 2.f / (e + 1.f);
  return v < 0.f ? -r : r;
}

#define DOT_U(g, u, A)                      \
  A = dot2f(W##g##_##u.x, hv0_.x, A);       \
  A = dot2f(W##g##_##u.y, hv0_.y, A);       \
  A = dot2f(W##g##_##u.z, hv0_.z, A);       \
  A = dot2f(W##g##_##u.w, hv0_.w, A);

#define DOT_G(g, A)                                            \
  { const uint4 hv0_ = hp[0]; DOT_U(g, 0, A) }                 \
  { const uint4 hv0_ = hp[1]; DOT_U(g, 1, A) }                 \
  { const uint4 hv0_ = hp[2]; DOT_U(g, 2, A) }                 \
  { const uint4 hv0_ = hp[3]; DOT_U(g, 3, A) }                 \
  { const uint4 hv0_ = hp[4]; DOT_U(g, 4, A) }                 \
  { const uint4 hv0_ = hp[5]; DOT_U(g, 5, A) }

// pin a uint4 into VGPRs: volatile asm cannot be remat'd/sunk/deleted
#define PIN4(v) asm volatile("" : "+v"(v.x), "+v"(v.y), "+v"(v.z), "+v"(v.w));

__global__ __launch_bounds__(512, 2)
void lstm_persist(const float* __restrict__ x,   const float* __restrict__ Wih,
                  const float* __restrict__ Whh, const float* __restrict__ bih,
                  const float* __restrict__ bhh, const float* __restrict__ Wout,
                  const float* __restrict__ bout_g, float* __restrict__ out,
                  uint64_t* exch)
{
  // hx: 2 rows x 192 dwords of fp16 pairs; row = [x_t(128 fp16) | h(256 fp16)]
  __shared__ alignas(16) uint32_t hx[2 * 192];

  const int tid = threadIdx.x;
  const int w   = blockIdx.x;
  const int p   = w & 63;                 // batch pair -> rows 2p, 2p+1
  const int q   = w >> 6;                 // hidden quarter; quartet same-XCD
  const int jj  = tid >> 3;               // 0..63 hidden unit within quarter
  const int ks  = tid & 7;                // 0..7 K-slice (48 fused K each)
  const int rbase = (q << 6) + jj;        // gate-row base within a gate block
  const int kb    = ks * 48;

  // ---- weights: 24 named uint4 (96 dwords), pinned to VGPRs
  uint4 W0_0, W0_1, W0_2, W0_3, W0_4, W0_5;
  uint4 W1_0, W1_1, W1_2, W1_3, W1_4, W1_5;
  uint4 W2_0, W2_1, W2_2, W2_3, W2_4, W2_5;
  uint4 W3_0, W3_1, W3_2, W3_3, W3_4, W3_5;
#define LOADG(g)                                             \
  { const int row = (g) * HID + rbase;                       \
    W##g##_0 = load8(Wih, Whh, row, kb +  0);                \
    W##g##_1 = load8(Wih, Whh, row, kb +  8);                \
    W##g##_2 = load8(Wih, Whh, row, kb + 16);                \
    W##g##_3 = load8(Wih, Whh, row, kb + 24);                \
    W##g##_4 = load8(Wih, Whh, row, kb + 32);                \
    W##g##_5 = load8(Wih, Whh, row, kb + 40); }
  LOADG(0) LOADG(1) LOADG(2) LOADG(3)
#undef LOADG
  PIN4(W0_0) PIN4(W0_1) PIN4(W0_2) PIN4(W0_3) PIN4(W0_4) PIN4(W0_5)
  PIN4(W1_0) PIN4(W1_1) PIN4(W1_2) PIN4(W1_3) PIN4(W1_4) PIN4(W1_5)
  PIN4(W2_0) PIN4(W2_1) PIN4(W2_2) PIN4(W2_3) PIN4(W2_4) PIN4(W2_5)
  PIN4(W3_0) PIN4(W3_1) PIN4(W3_2) PIN4(W3_3) PIN4(W3_4) PIN4(W3_5)

  // ---- gate biases (used by ks<2 lanes)
  float b0 = bih[0 * HID + rbase] + bhh[0 * HID + rbase];
  float b1 = bih[1 * HID + rbase] + bhh[1 * HID + rbase];
  float b2 = bih[2 * HID + rbase] + bhh[2 * HID + rbase];
  float b3 = bih[3 * HID + rbase] + bhh[3 * HID + rbase];

  // ---- out-projection: thread (oo,r,os): o = q*16+oo, K-slice os*16..+16
  const int oo = tid >> 5, orow = (tid >> 4) & 1, os = tid & 15;
  uint4 woA, woB;
  {
    const float* wo = Wout + (size_t)((q << 4) + oo) * HID + (os << 4);
    const float4 v0 = *(const float4*)(wo + 0), v1 = *(const float4*)(wo + 4);
    const float4 v2 = *(const float4*)(wo + 8), v3 = *(const float4*)(wo + 12);
    woA.x = pack2(v0.x, v0.y); woA.y = pack2(v0.z, v0.w);
    woA.z = pack2(v1.x, v1.y); woA.w = pack2(v1.z, v1.w);
    woB.x = pack2(v2.x, v2.y); woB.y = pack2(v2.z, v2.w);
    woB.z = pack2(v3.x, v3.y); woB.w = pack2(v3.z, v3.w);
  }
  PIN4(woA) PIN4(woB)
  const float bo = bout_g[(q << 4) + oo];

  // ---- init hx: h=0, x-part = x[0]
  if (tid < 256) hx[(tid >> 7) * 192 + 64 + (tid & 127)] = 0u;
  if (tid < 128) {
    const int row = tid >> 6, cc = tid & 63;
    const float2 xv = *(const float2*)(x + ((size_t)(2 * p + row)) * IN_D + 2 * cc);
    hx[row * 192 + cc] = pack2(xv.x, xv.y);
  }
  float c = 0.f;
  __syncthreads();

  for (int t = 0; t <= T_SEQ; ++t) {
    uint32_t xn = 0;
    uint32_t packed = 0;
    // ---------------- phase 1 ----------------
    if (t < T_SEQ) {
      if (tid >= 256 && tid < 384 && (t + 1) < T_SEQ) {
        const int row = (tid - 256) >> 6, cc = (tid - 256) & 63;
        const float2 xv = *(const float2*)(x + (size_t)(t + 1) * BATCH * IN_D +
                                           (size_t)(2 * p + row) * IN_D + 2 * cc);
        xn = pack2(xv.x, xv.y);
      }
      float a00 = 0.f, a10 = 0.f, a20 = 0.f, a30 = 0.f;
      float a01 = 0.f, a11 = 0.f, a21 = 0.f, a31 = 0.f;
      {
        const uint4* hp = (const uint4*)hx + ks * 6;           // row 0
        DOT_G(0, a00) DOT_G(1, a10) DOT_G(2, a20) DOT_G(3, a30)
      }
      {
        const uint4* hp = (const uint4*)hx + 48 + ks * 6;      // row 1
        DOT_G(0, a01) DOT_G(1, a11) DOT_G(2, a21) DOT_G(3, a31)
      }
      // select-tree reduction over the 8 ks lanes (16 shuffles)
      float u0, u1, u2, u3;
      {
        const int r = ks & 1;
        float t0, t1;
        t0 = a00 + __shfl_xor(a00, 1, 64); t1 = a01 + __shfl_xor(a01, 1, 64);
        u0 = r ? t1 : t0;
        t0 = a10 + __shfl_xor(a10, 1, 64); t1 = a11 + __shfl_xor(a11, 1, 64);
        u1 = r ? t1 : t0;
        t0 = a20 + __shfl_xor(a20, 1, 64); t1 = a21 + __shfl_xor(a21, 1, 64);
        u2 = r ? t1 : t0;
        t0 = a30 + __shfl_xor(a30, 1, 64); t1 = a31 + __shfl_xor(a31, 1, 64);
        u3 = r ? t1 : t0;
      }
      u0 += __shfl_xor(u0, 2, 64); u0 += __shfl_xor(u0, 4, 64);
      u1 += __shfl_xor(u1, 2, 64); u1 += __shfl_xor(u1, 4, 64);
      u2 += __shfl_xor(u2, 2, 64); u2 += __shfl_xor(u2, 4, 64);
      u3 += __shfl_xor(u3, 2, 64); u3 += __shfl_xor(u3, 4, 64);
      if (ks < 2) {   // lane ks holds all 4 gates for row r=ks
        const int r = ks;
        const float iv = sigm(b0 + u0), fv = sigm(b1 + u1);
        const float gv = tanhx(b2 + u2), ov = sigm(b3 + u3);
        c = fv * c + iv * gv;
        const float hn = ov * tanhx(c);
        union { _Float16 h; unsigned short u; } cv; cv.h = (_Float16)hn;
        const uint32_t mine  = cv.u;
        const uint32_t other = (uint32_t)(unsigned short)__shfl_xor((int)mine, 8, 64);
        if (!(jj & 1)) {
          packed = mine | (other << 16);   // h units (jj, jj+1) of row r
          // self-validating entry: {tag = t+1, data}; ONE 8B atomic store.
          const uint64_t entry = ((uint64_t)(uint32_t)(t + 1) << 32) | packed;
          __hip_atomic_store(
              exch + (((size_t)w << 7) | ((t & 1) << 6)) + (r << 5) + (jj >> 1),
              entry, __ATOMIC_RELAXED, __HIP_MEMORY_SCOPE_AGENT);
        }
      }
    }
    if (t >= 1) {  // out-projection for step t-1 from h(t-1) still in hx
      const uint4* hq = (const uint4*)hx + orow * 48 + 16 + os * 2;
      const uint4 h0 = hq[0], h1 = hq[1];
      float oa = 0.f;
      oa = dot2f(woA.x, h0.x, oa); oa = dot2f(woA.y, h0.y, oa);
      oa = dot2f(woA.z, h0.z, oa); oa = dot2f(woA.w, h0.w, oa);
      oa = dot2f(woB.x, h1.x, oa); oa = dot2f(woB.y, h1.y, oa);
      oa = dot2f(woB.z, h1.z, oa); oa = dot2f(woB.w, h1.w, oa);
      oa += __shfl_xor(oa, 1, 64); oa += __shfl_xor(oa, 2, 64);
      oa += __shfl_xor(oa, 4, 64); oa += __shfl_xor(oa, 8, 64);
      if (os == 0)
        out[((size_t)(t - 1) * BATCH + 2 * p + orow) * OUTD + (q << 4) + oo] = oa + bo;
    }
    __syncthreads();  // B1: all hx reads for step t done
    // ---------------- phase 2 ----------------
    if (t < T_SEQ) {
      if (ks < 2 && !(jj & 1))  // write own h pair into hx
        hx[ks * 192 + 64 + (q << 5) + (jj >> 1)] = packed;
      if (tid >= 256 && tid < 384 && (t + 1) < T_SEQ)
        hx[((tid - 256) >> 6) * 192 + ((tid - 256) & 63)] = xn;
      if (tid >= 64 && tid < 256) {  // consume 3 partner quarters
        const int i = tid - 64, qq = i >> 6, l = i & 63;
        const int qp = qq + (qq >= q);           // partner quarter != q
        const int ws = (qp << 6) | p;            // same-XCD partner
        const uint64_t* src =
            exch + (((size_t)ws << 7) | ((t & 1) << 6)) + l;
        const uint32_t want = (uint32_t)(t + 1);
        uint64_t e;
        do {
          e = __hip_atomic_load(src, __ATOMIC_RELAXED, __HIP_MEMORY_SCOPE_AGENT);
        } while ((uint32_t)(e >> 32) != want);
        hx[(l >> 5) * 192 + 64 + (qp << 5) + (l & 31)] = (uint32_t)e;
      }
    }
    __syncthreads();  // B2: hx fully assembled for step t+1
  }
}

extern "C" void kernel_launch(void* const* d_in, const int* in_sizes, int n_in,
                              void* d_out, int out_size, void* d_ws, size_t ws_size,
                              hipStream_t stream) {
  (void)in_sizes; (void)n_in; (void)out_size; (void)ws_size;
  const float* x    = (const float*)d_in[0];
  const float* Wih  = (const float*)d_in[1];
  const float* Whh  = (const float*)d_in[2];
  const float* bih  = (const float*)d_in[3];
  const float* bhh  = (const float*)d_in[4];
  const float* Wout = (const float*)d_in[5];
  const float* bout = (const float*)d_in[6];
  float* out = (float*)d_out;

  // exch: 256 WG x 2 ring slots x 64 entries x 8 B = 256 KiB in d_ws.
  // No memset needed: poison tag 0xAAAAAAAA never equals a valid tag 1..2048.
  uint64_t* exch = (uint64_t*)d_ws;

  hipLaunchKernelGGL(lstm_persist, dim3(256), dim3(512), 0, stream,
                     x, Wih, Whh, bih, bhh, Wout, bout, out, exch);
}